// Round 1
// baseline (2367.896 us; speedup 1.0000x reference)
//
#include <hip/hip_runtime.h>

constexpr int B = 16, C = 256, O = 256, H = 128, W = 128, K = 3;
constexpr int GROUPS = 32;
constexpr int CPG = C / GROUPS;   // 8 input channels per group
constexpr int OPG = O / GROUPS;   // 8 output channels per group
constexpr int HW = H * W;         // 16384
constexpr float EPS = 1e-7f;

constexpr int TILE = 32;
constexpr int HALO = TILE + 2;    // 34
constexpr int XSTR = 36;          // padded LDS row stride (float4-aligned rows)
constexpr int SELEM = HALO * HALO;  // 1156 staged elems per plane
// Buffer plane sized with slack so tail lanes (e in [1156,1280)) can write
// unconditionally into a pad region (max ladr = 37*36+21 = 1353) that compute
// never reads (compute reads < 34*36 = 1224).
constexpr int BPLANE = 1408;
constexpr int NW = CPG * K * K * OPG; // 576 combined weights per (b,g)

// ---------------- Kernel 1: per-(b,c) mean and 1/(std+eps) ----------------
__global__ __launch_bounds__(256) void stats_kernel(const float* __restrict__ x,
                                                    float2* __restrict__ stats) {
    int bc = blockIdx.x;                       // 0..B*C-1
    const float4* xv = (const float4*)(x + (size_t)bc * HW);
    int tid = threadIdx.x;
    float sum = 0.f, sumsq = 0.f;
#pragma unroll
    for (int it = 0; it < HW / 4 / 256; ++it) {  // 16 iters
        float4 v = xv[tid + it * 256];
        sum   += v.x + v.y + v.z + v.w;
        sumsq += v.x*v.x + v.y*v.y + v.z*v.z + v.w*v.w;
    }
#pragma unroll
    for (int off = 32; off > 0; off >>= 1) {
        sum   += __shfl_down(sum, off);
        sumsq += __shfl_down(sumsq, off);
    }
    __shared__ float s_sum[4], s_sq[4];
    int wave = tid >> 6;
    if ((tid & 63) == 0) { s_sum[wave] = sum; s_sq[wave] = sumsq; }
    __syncthreads();
    if (tid == 0) {
        float ts = s_sum[0] + s_sum[1] + s_sum[2] + s_sum[3];
        float tq = s_sq[0] + s_sq[1] + s_sq[2] + s_sq[3];
        float mean = ts / (float)HW;
        float var  = (tq - ts * ts / (float)HW) / (float)(HW - 1); // ddof=1
        var = fmaxf(var, 0.f);
        float stdv = sqrtf(var) + EPS;                             // eps on std, like torch
        stats[bc] = make_float2(mean, 1.0f / stdv);
    }
}

// ---------------- Kernel 2: fold 1x1 conv AND 1/std into 3x3 weights ----------------
// CW[b][g][i][ky][kx][o'] = istd_i * sum_j pw[b, g*OPG+o', j] * dw[b, g*OPG+j, i, ky, kx]
__global__ __launch_bounds__(256) void combine_kernel(const float* __restrict__ dw,
                                                      const float* __restrict__ pw,
                                                      const float2* __restrict__ stats,
                                                      float* __restrict__ cw) {
    int idx = blockIdx.x * 256 + threadIdx.x;   // exactly B*GROUPS*NW threads
    int o  = idx % OPG;  int t = idx / OPG;
    int kx = t % K;      t /= K;
    int ky = t % K;      t /= K;
    int i  = t % CPG;    t /= CPG;
    int g  = t % GROUPS; int b = t / GROUPS;
    const float* pwp = pw + (size_t)(b * O + g * OPG + o) * CPG;
    float acc = 0.f;
#pragma unroll
    for (int j = 0; j < CPG; ++j) {
        float wd = dw[(((size_t)(b * O + g * OPG + j) * CPG + i) * K + ky) * K + kx];
        acc = fmaf(pwp[j], wd, acc);
    }
    float istd = stats[b * C + g * CPG + i].y;
    cw[idx] = acc * istd;
}

// ---------------- Kernel 3: fused conv + bias ----------------
// Normalization is folded: weights already carry 1/std; the mean term is folded
// into an adjusted bias (bias - sum_{i,k} w2*m_i), with OOB taps staged as m_i
// so (m_i - m_i)*istd == 0 matches the reference's zero-padded normalized input.
// Per-channel double-buffered LDS staging: LDS ~13.3 KB -> 6 blocks/CU
// (vs 41 KB -> 3 blocks/CU before). Pipeline per i: load(i+1) global->regs,
// compute(i) from LDS, write(i+1) regs->LDS, one barrier.
__global__ __launch_bounds__(256, 6) void conv_kernel(const float* __restrict__ x,
                                                      const float* __restrict__ cw,
                                                      const float* __restrict__ bias,
                                                      const float2* __restrict__ stats,
                                                      float* __restrict__ out) {
    __shared__ float sw[NW];             // 2304 B
    __shared__ float sx[2][BPLANE];      // 11264 B
    __shared__ float sbias[OPG];         // 32 B

    int blk  = blockIdx.x;
    int tile = blk & 15;          // 16 tiles per (b,g)
    int g    = (blk >> 4) & 31;
    int b    = blk >> 9;
    int x0g  = (tile & 3) * TILE;
    int y0g  = (tile >> 2) * TILE;
    int tid  = threadIdx.x;

    // stage combined weights
    const float* cwp = cw + (size_t)(b * GROUPS + g) * NW;
    for (int e = tid; e < NW; e += 256) sw[e] = cwp[e];

    const float2* stp  = stats + b * C + g * CPG;
    const float* xbase = x + (size_t)(b * C + g * CPG) * HW;

    // i-invariant staging decode: 5 elements per thread covering 34x34 halo tile
    int ladr[5]; int gofs[5]; bool vm[5];
#pragma unroll
    for (int j = 0; j < 5; ++j) {
        int e = tid + j * 256;            // < 1280
        int r = e / HALO;
        int c = e - r * HALO;
        int gy = y0g + r - 1, gx = x0g + c - 1;
        bool v = (e < SELEM) && gy >= 0 && gy < H && gx >= 0 && gx < W;
        vm[j]   = v;
        gofs[j] = v ? gy * W + gx : 0;    // clamped: masked lanes read elem 0 (safe)
        ladr[j] = r * XSTR + c;           // tail lanes land in pad region of buffer
    }

    auto stage_load = [&](int i, float (&rv)[5]) {
        const float* xp = xbase + (size_t)i * HW;
#pragma unroll
        for (int j = 0; j < 5; ++j) rv[j] = xp[gofs[j]];
    };
    // select vs mean deferred to write time so the vmcnt wait lands late (T14)
    auto stage_write = [&](int i, float* dst, float (&rv)[5]) {
        float mi = stp[i].x;
#pragma unroll
        for (int j = 0; j < 5; ++j) dst[ladr[j]] = vm[j] ? rv[j] : mi;
    };

    // prologue: stage plane 0
    {
        float rv0[5];
        stage_load(0, rv0);
        stage_write(0, sx[0], rv0);
    }
    __syncthreads();

    // adjusted bias: sbias[o] = bias[o] - sum_{i,ky,kx} sw[i,ky,kx,o]*mean_i
    // wave 0 only (uniform branch), lane (o=tid&7, ii=tid>>3), shfl-reduce over ii
    if (tid < 64) {
        int o = tid & 7, ii = tid >> 3;
        float m = stp[ii].x;
        float p = 0.f;
#pragma unroll
        for (int t9 = 0; t9 < 9; ++t9) p += sw[(ii * 9 + t9) * OPG + o] * m;
#pragma unroll
        for (int d = 8; d < 64; d <<= 1) p += __shfl_xor(p, d);
        if (tid < OPG) sbias[tid] = bias[b * O + g * OPG + tid] - p;
    }

    // each thread: 4 contiguous pixels in x, all 8 output channels
    int xl = (tid & 7) * 4;      // local pixel x of first of 4
    int py = tid >> 3;           // local pixel y (0..31)

    float acc[OPG][4];
#pragma unroll
    for (int o = 0; o < OPG; ++o)
#pragma unroll
        for (int p = 0; p < 4; ++p) acc[o][p] = 0.f;

#pragma unroll 1
    for (int i = 0; i < CPG; ++i) {
        float rv[5];
        if (i + 1 < CPG) stage_load(i + 1, rv);   // loads in flight across compute

        const float* bufp = sx[i & 1];
#pragma unroll
        for (int ky = 0; ky < K; ++ky) {
            const float* rp = bufp + (py + ky) * XSTR + xl;
            float4 a  = *(const float4*)rp;        // 16B aligned
            float2 b2 = *(const float2*)(rp + 4);
            float xv[6] = {a.x, a.y, a.z, a.w, b2.x, b2.y};
#pragma unroll
            for (int kx = 0; kx < K; ++kx) {
                const float* wp = &sw[((i * K + ky) * K + kx) * OPG];
                float4 w0 = *(const float4*)wp;    // broadcast, cheap
                float4 w1 = *(const float4*)(wp + 4);
                float wv[8] = {w0.x, w0.y, w0.z, w0.w, w1.x, w1.y, w1.z, w1.w};
#pragma unroll
                for (int o = 0; o < OPG; ++o)
#pragma unroll
                    for (int p = 0; p < 4; ++p)
                        acc[o][p] = fmaf(wv[o], xv[kx + p], acc[o][p]);
            }
        }

        if (i + 1 < CPG) stage_write(i + 1, sx[(i + 1) & 1], rv);
        __syncthreads();
    }

    // epilogue: add adjusted bias, store float4 per output channel
    int gy = y0g + py, gxs = x0g + xl;
    float* op = out + (((size_t)(b * O + g * OPG) * H + gy) * W + gxs);
#pragma unroll
    for (int o = 0; o < OPG; ++o) {
        float bv = sbias[o];
        float4 r = make_float4(acc[o][0] + bv, acc[o][1] + bv,
                               acc[o][2] + bv, acc[o][3] + bv);
        *(float4*)(op + (size_t)o * HW) = r;
    }
}

extern "C" void kernel_launch(void* const* d_in, const int* in_sizes, int n_in,
                              void* d_out, int out_size, void* d_ws, size_t ws_size,
                              hipStream_t stream) {
    const float* x    = (const float*)d_in[0];
    const float* dw   = (const float*)d_in[1];
    const float* pw   = (const float*)d_in[2];
    const float* bias = (const float*)d_in[3];
    float* out = (float*)d_out;

    // workspace layout: stats (B*C float2 = 32 KB), then combined weights (1.18 MB)
    float2* stats = (float2*)d_ws;
    float*  cwbuf = (float*)((char*)d_ws + B * C * sizeof(float2));

    stats_kernel<<<B * C, 256, 0, stream>>>(x, stats);
    combine_kernel<<<(B * GROUPS * NW) / 256, 256, 0, stream>>>(dw, pw, stats, cwbuf);
    conv_kernel<<<B * GROUPS * 16, 256, 0, stream>>>(x, cwbuf, bias, stats, out);
}

// Round 2
// 623.677 us; speedup vs baseline: 3.7967x; 3.7967x over previous
//
#include <hip/hip_runtime.h>

constexpr int B = 16, C = 256, O = 256, H = 128, W = 128, K = 3;
constexpr int GROUPS = 32;
constexpr int CPG = C / GROUPS;   // 8 input channels per group
constexpr int OPG = O / GROUPS;   // 8 output channels per group
constexpr int HW = H * W;         // 16384
constexpr float EPS = 1e-7f;

constexpr int NT = 512;           // 2 o-halves x 256 pixel-threads
constexpr int TILE = 32;
constexpr int HALO = TILE + 2;    // 34
// XSTR=40: x-row float4 reads hit bank (8*py+4*xc)%32 -> exactly 2 lanes/addr
// = conflict-free (2-way is free, m136). XSTR=36 was 8-way on 4-bank groups.
constexpr int XSTR = 40;
constexpr int SELEM = HALO * HALO;  // 1156 staged elems per plane
// 512 threads x 3 elems = 1536 staged slots; tail (e in [1156,1536)) writes
// land at ladr in [34*40, 45*40+5] = [1360, 1805] -- pad region, compute
// reads only < 33*40+34 = 1354.
constexpr int BPLANE = 1824;
constexpr int NW = CPG * K * K * OPG; // 576 combined weights per (b,g)

// ---------------- Kernel 1: per-(b,c) mean and 1/(std+eps) ----------------
__global__ __launch_bounds__(256) void stats_kernel(const float* __restrict__ x,
                                                    float2* __restrict__ stats) {
    int bc = blockIdx.x;                       // 0..B*C-1
    const float4* xv = (const float4*)(x + (size_t)bc * HW);
    int tid = threadIdx.x;
    float sum = 0.f, sumsq = 0.f;
#pragma unroll
    for (int it = 0; it < HW / 4 / 256; ++it) {  // 16 iters
        float4 v = xv[tid + it * 256];
        sum   += v.x + v.y + v.z + v.w;
        sumsq += v.x*v.x + v.y*v.y + v.z*v.z + v.w*v.w;
    }
#pragma unroll
    for (int off = 32; off > 0; off >>= 1) {
        sum   += __shfl_down(sum, off);
        sumsq += __shfl_down(sumsq, off);
    }
    __shared__ float s_sum[4], s_sq[4];
    int wave = tid >> 6;
    if ((tid & 63) == 0) { s_sum[wave] = sum; s_sq[wave] = sumsq; }
    __syncthreads();
    if (tid == 0) {
        float ts = s_sum[0] + s_sum[1] + s_sum[2] + s_sum[3];
        float tq = s_sq[0] + s_sq[1] + s_sq[2] + s_sq[3];
        float mean = ts / (float)HW;
        float var  = (tq - ts * ts / (float)HW) / (float)(HW - 1); // ddof=1
        var = fmaxf(var, 0.f);
        float stdv = sqrtf(var) + EPS;                             // eps on std, like torch
        stats[bc] = make_float2(mean, 1.0f / stdv);
    }
}

// ---------------- Kernel 2: fold 1x1 conv AND 1/std into 3x3 weights ----------------
// CW[b][g][i][ky][kx][o'] = istd_i * sum_j pw[b, g*OPG+o', j] * dw[b, g*OPG+j, i, ky, kx]
__global__ __launch_bounds__(256) void combine_kernel(const float* __restrict__ dw,
                                                      const float* __restrict__ pw,
                                                      const float2* __restrict__ stats,
                                                      float* __restrict__ cw) {
    int idx = blockIdx.x * 256 + threadIdx.x;   // exactly B*GROUPS*NW threads
    int o  = idx % OPG;  int t = idx / OPG;
    int kx = t % K;      t /= K;
    int ky = t % K;      t /= K;
    int i  = t % CPG;    t /= CPG;
    int g  = t % GROUPS; int b = t / GROUPS;
    const float* pwp = pw + (size_t)(b * O + g * OPG + o) * CPG;
    float acc = 0.f;
#pragma unroll
    for (int j = 0; j < CPG; ++j) {
        float wd = dw[(((size_t)(b * O + g * OPG + j) * CPG + i) * K + ky) * K + kx];
        acc = fmaf(pwp[j], wd, acc);
    }
    float istd = stats[b * C + g * CPG + i].y;
    cw[idx] = acc * istd;
}

// ---------------- Kernel 3: fused conv + bias ----------------
// Normalization folded into weights (1/std) and adjusted bias (mean term);
// OOB taps staged as mean so (m-m)*istd == 0 matches zero-padded normalized
// input. 512 threads: tid>>8 selects output-channel half (4 of 8), tid&255
// maps to pixels -> acc[4][4] = 16 regs, targeting <=64 VGPR for 2048
// threads/CU. Per-channel double-buffered LDS pipeline:
// load(i+1)->regs, compute(i), write(i+1)->LDS, one barrier per channel.
__global__ __launch_bounds__(512, 4) void conv_kernel(const float* __restrict__ x,
                                                      const float* __restrict__ cw,
                                                      const float* __restrict__ bias,
                                                      const float2* __restrict__ stats,
                                                      float* __restrict__ out) {
    __shared__ float sw[NW];             // 2304 B
    __shared__ float sx[2][BPLANE];      // 14592 B
    __shared__ float sbias[OPG];         // 32 B

    int blk  = blockIdx.x;
    int tile = blk & 15;          // 16 tiles per (b,g)
    int g    = (blk >> 4) & 31;
    int b    = blk >> 9;
    int x0g  = (tile & 3) * TILE;
    int y0g  = (tile >> 2) * TILE;
    int tid  = threadIdx.x;

    // stage combined weights
    const float* cwp = cw + (size_t)(b * GROUPS + g) * NW;
    for (int e = tid; e < NW; e += NT) sw[e] = cwp[e];

    const float2* stp  = stats + b * C + g * CPG;
    const float* xbase = x + (size_t)(b * C + g * CPG) * HW;

    // i-invariant staging decode: 3 elements per thread covering 34x34 halo tile
    int ladr[3]; int gofs[3]; bool vm[3];
#pragma unroll
    for (int j = 0; j < 3; ++j) {
        int e = tid + j * NT;             // < 1536
        int r = e / HALO;
        int c = e - r * HALO;
        int gy = y0g + r - 1, gx = x0g + c - 1;
        bool v = (e < SELEM) && gy >= 0 && gy < H && gx >= 0 && gx < W;
        vm[j]   = v;
        gofs[j] = v ? gy * W + gx : 0;    // clamped: masked lanes read elem 0 (safe)
        ladr[j] = r * XSTR + c;           // tail lanes land in pad region of buffer
    }

    auto stage_load = [&](int i, float (&rv)[3]) {
        const float* xp = xbase + (size_t)i * HW;
#pragma unroll
        for (int j = 0; j < 3; ++j) rv[j] = xp[gofs[j]];
    };
    // select vs mean deferred to write time so the vmcnt wait lands late (T14)
    auto stage_write = [&](int i, float* dst, float (&rv)[3]) {
        float mi = stp[i].x;
#pragma unroll
        for (int j = 0; j < 3; ++j) dst[ladr[j]] = vm[j] ? rv[j] : mi;
    };

    // prologue: stage plane 0
    {
        float rv0[3];
        stage_load(0, rv0);
        stage_write(0, sx[0], rv0);
    }
    __syncthreads();

    // adjusted bias: sbias[o] = bias[o] - sum_{i,ky,kx} sw[i,ky,kx,o]*mean_i
    // wave 0 only (uniform branch), lane (o=tid&7, ii=tid>>3), shfl-reduce over ii
    if (tid < 64) {
        int o = tid & 7, ii = tid >> 3;
        float m = stp[ii].x;
        float p = 0.f;
#pragma unroll
        for (int t9 = 0; t9 < 9; ++t9) p += sw[(ii * 9 + t9) * OPG + o] * m;
#pragma unroll
        for (int d = 8; d < 64; d <<= 1) p += __shfl_xor(p, d);
        if (tid < OPG) sbias[tid] = bias[b * O + g * OPG + tid] - p;
    }

    // pixel mapping: 256 pixel-threads x 2 o-halves
    int oh = tid >> 8;           // output-channel half (0/1)
    int t8 = tid & 255;
    int xl = (t8 & 7) * 4;       // local pixel x of first of 4
    int py = t8 >> 3;            // local pixel y (0..31)

    float acc[4][4];
#pragma unroll
    for (int o = 0; o < 4; ++o)
#pragma unroll
        for (int p = 0; p < 4; ++p) acc[o][p] = 0.f;

#pragma unroll 1
    for (int i = 0; i < CPG; ++i) {
        float rv[3];
        if (i + 1 < CPG) stage_load(i + 1, rv);   // loads in flight across compute

        const float* bufp = sx[i & 1];
#pragma unroll
        for (int ky = 0; ky < K; ++ky) {
            const float* rp = bufp + (py + ky) * XSTR + xl;
            float4 a  = *(const float4*)rp;        // 16B aligned
            float2 b2 = *(const float2*)(rp + 4);
            float xv[6] = {a.x, a.y, a.z, a.w, b2.x, b2.y};
#pragma unroll
            for (int kx = 0; kx < K; ++kx) {
                // 4 weights for this thread's o-half; 16B aligned, wave-uniform
                const float* wp = &sw[((i * K + ky) * K + kx) * OPG + oh * 4];
                float4 w = *(const float4*)wp;
                float wv[4] = {w.x, w.y, w.z, w.w};
#pragma unroll
                for (int o = 0; o < 4; ++o)
#pragma unroll
                    for (int p = 0; p < 4; ++p)
                        acc[o][p] = fmaf(wv[o], xv[kx + p], acc[o][p]);
            }
        }

        if (i + 1 < CPG) stage_write(i + 1, sx[(i + 1) & 1], rv);
        __syncthreads();
    }

    // epilogue: add adjusted bias, store float4 per output channel
    int gy = y0g + py, gxs = x0g + xl;
    float* op = out + (((size_t)(b * O + g * OPG + oh * 4) * H + gy) * W + gxs);
#pragma unroll
    for (int o = 0; o < 4; ++o) {
        float bv = sbias[oh * 4 + o];
        float4 r = make_float4(acc[o][0] + bv, acc[o][1] + bv,
                               acc[o][2] + bv, acc[o][3] + bv);
        *(float4*)(op + (size_t)o * HW) = r;
    }
}

extern "C" void kernel_launch(void* const* d_in, const int* in_sizes, int n_in,
                              void* d_out, int out_size, void* d_ws, size_t ws_size,
                              hipStream_t stream) {
    const float* x    = (const float*)d_in[0];
    const float* dw   = (const float*)d_in[1];
    const float* pw   = (const float*)d_in[2];
    const float* bias = (const float*)d_in[3];
    float* out = (float*)d_out;

    // workspace layout: stats (B*C float2 = 32 KB), then combined weights (1.18 MB)
    float2* stats = (float2*)d_ws;
    float*  cwbuf = (float*)((char*)d_ws + B * C * sizeof(float2));

    stats_kernel<<<B * C, 256, 0, stream>>>(x, stats);
    combine_kernel<<<(B * GROUPS * NW) / 256, 256, 0, stream>>>(dw, pw, stats, cwbuf);
    conv_kernel<<<B * GROUPS * 16, 512, 0, stream>>>(x, cwbuf, bias, stats, out);
}